// Round 12
// baseline (374.953 us; speedup 1.0000x reference)
//
#include <hip/hip_runtime.h>
#include <hip/hip_bf16.h>

// TemporalAttention fused kernel for MI355X (gfx950), round 12.
// TWO sequences per block (1300 blocks x 512 thr): each staged W ks-image
// feeds both sequences' MFMAs -> per-seq staging cost, pipeline fills and
// barriers halve. W staging via global_load_lds with the read-swizzle baked
// into the prep-kernel layout (G21: linear LDS dest + pre-swizzled global
// source + swizzled read) -> zero staging VGPRs/ds_writes, single 48KB W
// buffer, 2-phase pipeline {read frags; lgkm-bar; issue ks+1; MFMA; sync}.
// LDS 112KB. launch_bounds(512,1): 256-VGPR budget for 2-seq accumulators.

namespace {

constexpr int S_LEN = 64;
constexpr int DM    = 256;
constexpr int SD    = S_LEN * DM;
constexpr int QKV_UNITS = 8 * 768 * 4;   // 24576 16B-units in wqt
// wpt units: 8 * 256 * 4 = 8192; total 32768 units

typedef float f32x4 __attribute__((ext_vector_type(4)));
typedef short s16x8 __attribute__((ext_vector_type(8)));

union BF2 { __hip_bfloat162 h; unsigned u; };
__device__ __forceinline__ unsigned pkbf2(float a, float b) {
  float2 t; t.x = a; t.y = b;
  BF2 cv; cv.h = __float22bfloat162_rn(t);
  return cv.u;
}

// lgkm-only block barrier (R11-verified): does NOT drain vmcnt.
__device__ __forceinline__ void bar_lgkm() {
  asm volatile("s_waitcnt lgkmcnt(0)" ::: "memory");
  __builtin_amdgcn_sched_barrier(0);
  __builtin_amdgcn_s_barrier();
  __builtin_amdgcn_sched_barrier(0);
}

// In-register fragment transpose (verified rounds 3-11).
__device__ __forceinline__ s16x8 xpose_frag(f32x4 a0, f32x4 a1, int c, int g) {
  const int src0 = ((g & 1) << 5) + c;
  const int src1 = src0 + 16;
  unsigned p00 = pkbf2(a0[0], a0[1]);
  unsigned p01 = pkbf2(a0[2], a0[3]);
  unsigned p10 = pkbf2(a1[0], a1[1]);
  unsigned p11 = pkbf2(a1[2], a1[3]);
  const bool hi = (g & 2) != 0;
  unsigned w0a = (unsigned)__shfl((int)p00, src0);
  unsigned w0b = (unsigned)__shfl((int)p10, src0);
  unsigned w1a = (unsigned)__shfl((int)p01, src0);
  unsigned w1b = (unsigned)__shfl((int)p11, src0);
  unsigned w2a = (unsigned)__shfl((int)p00, src1);
  unsigned w2b = (unsigned)__shfl((int)p10, src1);
  unsigned w3a = (unsigned)__shfl((int)p01, src1);
  unsigned w3b = (unsigned)__shfl((int)p11, src1);
  union { s16x8 v; unsigned u[4]; } r;
  r.u[0] = hi ? w0b : w0a;
  r.u[1] = hi ? w1b : w1a;
  r.u[2] = hi ? w2b : w2a;
  r.u[3] = hi ? w3b : w3a;
  return r.v;
}

// W LDS read addressing (R9-verified): image [rows][32] bf16,
// 16B-unit swizzle u' = g ^ ((row>>1)&3). Prep kernel bakes the inverse
// into the global layout so global_load_lds can write linearly.
__device__ __forceinline__ int wswz(int row, int u) {
  return row * 32 + ((u ^ ((row >> 1) & 3)) << 3);
}

// attention middle for one sequence (R11 math verbatim; vb prebuilt)
__device__ __forceinline__ void attn_middle(
    const f32x4 (&aq)[2][4], const f32x4 (&ak)[2][4], const s16x8 (&vb)[2][2],
    int c, int g, unsigned (&obp)[4][2][2])
{
  s16x8 qa[4], ka[4];
#pragma unroll
  for (int i = 0; i < 4; ++i) {
    qa[i] = xpose_frag(aq[0][i], aq[1][i], c, g);
    ka[i] = xpose_frag(ak[0][i], ak[1][i], c, g);
  }
  f32x4 sa[4][4];
#pragma unroll
  for (int ki = 0; ki < 4; ++ki)
#pragma unroll
    for (int qi = 0; qi < 4; ++qi) {
      f32x4 z = f32x4{0.f, 0.f, 0.f, 0.f};
      sa[ki][qi] = __builtin_amdgcn_mfma_f32_16x16x32_bf16(ka[ki], qa[qi], z, 0, 0, 0);
    }
  const float sc = 0.17677669529663687f * 1.4426950408889634f;
  float inv[4];
#pragma unroll
  for (int qi = 0; qi < 4; ++qi) {
    float m = sa[0][qi][0];
#pragma unroll
    for (int ki = 0; ki < 4; ++ki)
#pragma unroll
      for (int r = 0; r < 4; ++r) m = fmaxf(m, sa[ki][qi][r]);
    m = fmaxf(m, __shfl_xor(m, 16));
    m = fmaxf(m, __shfl_xor(m, 32));
    float s = 0.0f;
#pragma unroll
    for (int ki = 0; ki < 4; ++ki)
#pragma unroll
      for (int r = 0; r < 4; ++r) {
        float pv = exp2f((sa[ki][qi][r] - m) * sc);
        sa[ki][qi][r] = pv;
        s += pv;
      }
    s += __shfl_xor(s, 16);
    s += __shfl_xor(s, 32);
    inv[qi] = 1.0f / s;
  }
  s16x8 pa[4][2];
#pragma unroll
  for (int mi = 0; mi < 4; ++mi) {
    const float iv = inv[mi];
#pragma unroll
    for (int ks2 = 0; ks2 < 2; ++ks2) {
      f32x4 v0 = sa[2 * ks2][mi] * iv;
      f32x4 v1 = sa[2 * ks2 + 1][mi] * iv;
      pa[mi][ks2] = xpose_frag(v0, v1, c, g);
    }
  }
  f32x4 oa[4][2];
#pragma unroll
  for (int mi = 0; mi < 4; ++mi)
#pragma unroll
    for (int nd = 0; nd < 2; ++nd) oa[mi][nd] = f32x4{0.f, 0.f, 0.f, 0.f};
#pragma unroll
  for (int ks2 = 0; ks2 < 2; ++ks2)
#pragma unroll
    for (int mi = 0; mi < 4; ++mi)
#pragma unroll
      for (int nd = 0; nd < 2; ++nd)
        oa[mi][nd] = __builtin_amdgcn_mfma_f32_16x16x32_bf16(pa[mi][ks2], vb[nd][ks2], oa[mi][nd], 0, 0, 0);
#pragma unroll
  for (int mi = 0; mi < 4; ++mi)
#pragma unroll
    for (int nd = 0; nd < 2; ++nd) {
      obp[mi][nd][0] = pkbf2(oa[mi][nd][0], oa[mi][nd][1]);
      obp[mi][nd][1] = pkbf2(oa[mi][nd][2], oa[mi][nd][3]);
    }
}

} // namespace

// ---- prep: f32 weights -> bf16, per-ks images with baked read-swizzle ----
// wqt unit (ks,row,u) holds W_qkv[row][ks*32 + (u^s)*8 .. +8], s=(row>>1)&3.
// wpt likewise for w_proj. Unit index is linear -> global_load_lds dest linear.
__global__ void ta_prep_weights(const float* __restrict__ wqkv,
                                const float* __restrict__ wproj,
                                unsigned short* __restrict__ wsb) {
  const int o = blockIdx.x * 256 + (int)threadIdx.x;   // 16B-unit index
  const float* src;
  if (o < QKV_UNITS) {
    const int ks = o / 3072, rem = o - ks * 3072;
    const int row = rem >> 2, u = rem & 3;
    const int s = (row >> 1) & 3;
    src = wqkv + row * 256 + ks * 32 + ((u ^ s) << 3);
  } else {
    const int p = o - QKV_UNITS;
    const int ks = p >> 10, rem = p & 1023;
    const int row = rem >> 2, u = rem & 3;
    const int s = (row >> 1) & 3;
    src = wproj + row * 256 + ks * 32 + ((u ^ s) << 3);
  }
  f32x4 a = *(const f32x4*)src;
  f32x4 b = *(const f32x4*)(src + 4);
  *(uint4*)(wsb + (size_t)o * 8) =
      make_uint4(pkbf2(a[0], a[1]), pkbf2(a[2], a[3]),
                 pkbf2(b[0], b[1]), pkbf2(b[2], b[3]));
}

__global__ void __launch_bounds__(512, 1)
ta_fused_kernel(const float* __restrict__ x,
                const unsigned short* __restrict__ wqt,   // [8][768][4] units
                const float* __restrict__ bqkv,
                const unsigned short* __restrict__ wpt,   // [8][256][4] units
                const float* __restrict__ bproj,
                float* __restrict__ out)
{
  // LDS 112KB (57344 shorts):
  //  [0,16384)      X_A (swizzled bf16) -> att_A -> f32 out tile A
  //  [16384,32768)  X_B                 -> att_B -> f32 out tile B
  //  [32768,57344)  W image (48KB, single buffer, gload_lds-filled)
  __shared__ __align__(16) unsigned short lds[57344];

  const int tid = (int)threadIdx.x;
  const int w = tid >> 6;       // wave 0..7 = head
  const int l = tid & 63;
  const int g = l >> 4;
  const int c = l & 15;
  const int c7s = (c & 7) << 3;
  const int h = w;

  unsigned short* xls0 = lds;
  unsigned short* xls1 = lds + 16384;
  unsigned short* wb   = lds + 32768;

  const int bn0 = blockIdx.x * 2;
  const float* __restrict__ xbA = x + (size_t)bn0 * SD;
  const float* __restrict__ xbB = xbA + SD;

  // ---- issue W[ks=0] image (async, zero-VGPR, linear dest) ----
#pragma unroll
  for (int i = 0; i < 6; ++i) {
    const int n = i * 512 + tid;
    __builtin_amdgcn_global_load_lds(
        (const __attribute__((address_space(1))) unsigned int*)(wqt + (size_t)(0 * 3072 + n) * 8),
        (__attribute__((address_space(3))) unsigned int*)(wb + n * 8), 16, 0, 0);
  }

  // ---- stage X for both sequences (swizzled bf16) ----
#pragma unroll
  for (int s2 = 0; s2 < 2; ++s2) {
    const float* __restrict__ xb = s2 ? xbB : xbA;
    unsigned short* __restrict__ xd = s2 ? xls1 : xls0;
#pragma unroll
    for (int it = 0; it < 4; ++it) {
      const int e = (it * 512 + tid) * 8;
      const int row = e >> 8;
      f32x4 a = *(const f32x4*)(xb + e);
      f32x4 b = *(const f32x4*)(xb + e + 4);
      union { s16x8 v; unsigned u[4]; } r;
      r.u[0] = pkbf2(a[0], a[1]); r.u[1] = pkbf2(a[2], a[3]);
      r.u[2] = pkbf2(b[0], b[1]); r.u[3] = pkbf2(b[2], b[3]);
      *(s16x8*)&xd[e ^ ((row & 7) << 3)] = r.v;
    }
  }
  __syncthreads();   // X visible; W0 landed (vmcnt drained)

  // ---- merged Q/K/V sweep over 8 ks, BOTH sequences per staged image ----
  f32x4 aq[2][2][4], ak[2][2][4], av[2][4][2];   // [s2][..]
#pragma unroll
  for (int s2 = 0; s2 < 2; ++s2) {
#pragma unroll
    for (int t = 0; t < 2; ++t)
#pragma unroll
      for (int nj = 0; nj < 4; ++nj) {
        aq[s2][t][nj] = f32x4{0.f, 0.f, 0.f, 0.f};
        ak[s2][t][nj] = f32x4{0.f, 0.f, 0.f, 0.f};
      }
#pragma unroll
    for (int mt = 0; mt < 4; ++mt)
#pragma unroll
      for (int t = 0; t < 2; ++t) av[s2][mt][t] = f32x4{0.f, 0.f, 0.f, 0.f};
  }

#pragma unroll
  for (int ks = 0; ks < 8; ++ks) {
    // read this ks's W fragments into registers
    s16x8 awq[2], awk[2], awv[2];
#pragma unroll
    for (int t = 0; t < 2; ++t) {
      awq[t] = *(const s16x8*)&wb[wswz((2 * h + t) * 16 + c, g)];
      awk[t] = *(const s16x8*)&wb[wswz(256 + 32 * h + 16 * t + c, g)];
      awv[t] = *(const s16x8*)&wb[wswz(512 + 32 * h + 16 * t + c, g)];
    }
    bar_lgkm();                       // all waves' W reads complete
    if (ks < 7) {                     // refill the single buffer for ks+1
#pragma unroll
      for (int i = 0; i < 6; ++i) {
        const int n = i * 512 + tid;
        __builtin_amdgcn_global_load_lds(
            (const __attribute__((address_space(1))) unsigned int*)(wqt + (size_t)((ks + 1) * 3072 + n) * 8),
            (__attribute__((address_space(3))) unsigned int*)(wb + n * 8), 16, 0, 0);
      }
    }
    const int kof = ks * 32 + g * 8;
#pragma unroll
    for (int s2 = 0; s2 < 2; ++s2) {
      const unsigned short* xd = s2 ? xls1 : xls0;
      s16x8 bx[4];
#pragma unroll
      for (int nj = 0; nj < 4; ++nj) {
        const int row = 16 * nj + c;
        bx[nj] = *(const s16x8*)&xd[(row * 256 + kof) ^ c7s];
      }
#pragma unroll
      for (int t = 0; t < 2; ++t)
#pragma unroll
        for (int nj = 0; nj < 4; ++nj) {
          aq[s2][t][nj] = __builtin_amdgcn_mfma_f32_16x16x32_bf16(awq[t], bx[nj], aq[s2][t][nj], 0, 0, 0);
          ak[s2][t][nj] = __builtin_amdgcn_mfma_f32_16x16x32_bf16(awk[t], bx[nj], ak[s2][t][nj], 0, 0, 0);
          av[s2][nj][t] = __builtin_amdgcn_mfma_f32_16x16x32_bf16(bx[nj], awv[t], av[s2][nj][t], 0, 0, 0);
        }
    }
    __syncthreads();                  // ks+1 image landed; safe to read next
  }

  // ---- issue phaseC W[0] image (flies under the attention middles) ----
#pragma unroll
  for (int i = 0; i < 2; ++i) {
    const int n = i * 512 + tid;
    __builtin_amdgcn_global_load_lds(
        (const __attribute__((address_space(1))) unsigned int*)(wpt + (size_t)(0 * 1024 + n) * 8),
        (__attribute__((address_space(3))) unsigned int*)(wb + n * 8), 16, 0, 0);
  }

  // ---- biases ----
#pragma unroll
  for (int s2 = 0; s2 < 2; ++s2) {
#pragma unroll
    for (int t = 0; t < 2; ++t) {
      f32x4 bq = *(const f32x4*)(bqkv + (2 * h + t) * 16 + 4 * g);
      f32x4 bk = *(const f32x4*)(bqkv + 256 + 32 * h + 16 * t + 4 * g);
#pragma unroll
      for (int nj = 0; nj < 4; ++nj) {
        aq[s2][t][nj] += bq;
        ak[s2][t][nj] += bk;
      }
    }
    const float bv0 = bqkv[512 + 32 * h + c];
    const float bv1 = bqkv[512 + 32 * h + 16 + c];
#pragma unroll
    for (int mt = 0; mt < 4; ++mt)
#pragma unroll
      for (int r = 0; r < 4; ++r) {
        av[s2][mt][0][r] += bv0;
        av[s2][mt][1][r] += bv1;
      }
  }

  // ---- V fragments early (frees 64 acc VGPRs before the middles) ----
  s16x8 vb[2][2][2];   // [s2][nd][ks2]
#pragma unroll
  for (int s2 = 0; s2 < 2; ++s2)
#pragma unroll
    for (int nd = 0; nd < 2; ++nd)
#pragma unroll
      for (int ks2 = 0; ks2 < 2; ++ks2)
        vb[s2][nd][ks2] = xpose_frag(av[s2][2 * ks2][nd], av[s2][2 * ks2 + 1][nd], c, g);

  // ---- attention middles (seq A fully, then seq B) ----
  unsigned obp[2][4][2][2];
  attn_middle(aq[0], ak[0], vb[0], c, g, obp[0]);
  attn_middle(aq[1], ak[1], vb[1], c, g, obp[1]);

  // ---- scatter O into att overlays (X reads all done at last sweep barrier) ----
#pragma unroll
  for (int s2 = 0; s2 < 2; ++s2) {
    unsigned short* att = s2 ? xls1 : xls0;
#pragma unroll
    for (int mi = 0; mi < 4; ++mi)
#pragma unroll
      for (int nd = 0; nd < 2; ++nd)
#pragma unroll
        for (int r = 0; r < 4; ++r) {
          const int q = 16 * mi + 4 * g + r;
          const int feat = h * 32 + 16 * nd + c;
          unsigned val = obp[s2][mi][nd][r >> 1] >> (16 * (r & 1));
          att[(q * 256 + feat) ^ ((q & 7) << 3)] = (unsigned short)val;
        }
  }
  __syncthreads();   // att visible + phaseC W0 landed (vmcnt drained)

  // ---- Phase C: out^T = Wproj @ att^T, both sequences per staged image ----
  f32x4 pacc[2][2][4];   // [s2][ti][nj]
#pragma unroll
  for (int s2 = 0; s2 < 2; ++s2)
#pragma unroll
    for (int ti = 0; ti < 2; ++ti)
#pragma unroll
      for (int nj = 0; nj < 4; ++nj) pacc[s2][ti][nj] = f32x4{0.f, 0.f, 0.f, 0.f};

#pragma unroll
  for (int ks = 0; ks < 8; ++ks) {
    s16x8 aw[2];
#pragma unroll
    for (int ti = 0; ti < 2; ++ti)
      aw[ti] = *(const s16x8*)&wb[wswz((2 * w + ti) * 16 + c, g)];
    bar_lgkm();
    if (ks < 7) {
#pragma unroll
      for (int i = 0; i < 2; ++i) {
        const int n = i * 512 + tid;
        __builtin_amdgcn_global_load_lds(
            (const __attribute__((address_space(1))) unsigned int*)(wpt + (size_t)((ks + 1) * 1024 + n) * 8),
            (__attribute__((address_space(3))) unsigned int*)(wb + n * 8), 16, 0, 0);
      }
    }
    const int kof = ks * 32 + 8 * g;
#pragma unroll
    for (int s2 = 0; s2 < 2; ++s2) {
      const unsigned short* att = s2 ? xls1 : xls0;
      s16x8 bx[4];
#pragma unroll
      for (int nj = 0; nj < 4; ++nj) {
        const int row = 16 * nj + c;
        bx[nj] = *(const s16x8*)&att[(row * 256 + kof) ^ c7s];
      }
#pragma unroll
      for (int ti = 0; ti < 2; ++ti)
#pragma unroll
        for (int nj = 0; nj < 4; ++nj)
          pacc[s2][ti][nj] = __builtin_amdgcn_mfma_f32_16x16x32_bf16(aw[ti], bx[nj], pacc[s2][ti][nj], 0, 0, 0);
    }
    __syncthreads();
  }

  // ---- epilogue: per half-H, both sequences' f32 tiles overlay their X regions ----
#pragma unroll
  for (int H = 0; H < 2; ++H) {
#pragma unroll
    for (int s2 = 0; s2 < 2; ++s2) {
      float* ldsf = (float*)(s2 ? xls1 : xls0);
#pragma unroll
      for (int ti = 0; ti < 2; ++ti) {
        const int e0 = (2 * w + ti) * 16 + 4 * g;
        f32x4 bp = *(const f32x4*)(bproj + e0);
#pragma unroll
        for (int nj = 2 * H; nj < 2 * H + 2; ++nj) {
          const int lr = 16 * (nj - 2 * H) + c;
          f32x4 v;
          v[0] = pacc[s2][ti][nj][0] + bp[0];
          v[1] = pacc[s2][ti][nj][1] + bp[1];
          v[2] = pacc[s2][ti][nj][2] + bp[2];
          v[3] = pacc[s2][ti][nj][3] + bp[3];
          *(f32x4*)&ldsf[(lr * 256 + e0) ^ ((lr & 7) << 2)] = v;
        }
      }
    }
    bar_lgkm();
#pragma unroll
    for (int s2 = 0; s2 < 2; ++s2) {
      const float* ldsf = (const float*)(s2 ? xls1 : xls0);
      float* __restrict__ ob = out + (size_t)(bn0 + s2) * SD;
#pragma unroll
      for (int it = 0; it < 4; ++it) {
        const int i = (it * 512 + tid) * 4;
        const int lr = i >> 8;
        f32x4 v = *(const f32x4*)&ldsf[i ^ ((lr & 7) << 2)];
        *(f32x4*)(ob + H * 8192 + i) = v;
      }
    }
    if (H == 0) bar_lgkm();
  }
}

extern "C" void kernel_launch(void* const* d_in, const int* in_sizes, int n_in,
                              void* d_out, int out_size, void* d_ws, size_t ws_size,
                              hipStream_t stream) {
  (void)n_in; (void)ws_size; (void)out_size;
  const float* x     = (const float*)d_in[0];
  const float* wqkv  = (const float*)d_in[1];
  const float* bqkv  = (const float*)d_in[2];
  const float* wproj = (const float*)d_in[3];
  const float* bproj = (const float*)d_in[4];
  float* out = (float*)d_out;

  unsigned short* wsb = (unsigned short*)d_ws;
  const unsigned short* wqt = wsb;                   // [8][768][4] 16B-units
  const unsigned short* wpt = wsb + QKV_UNITS * 8;   // [8][256][4]

  // 32768 units / 256 per block = 128 blocks
  hipLaunchKernelGGL(ta_prep_weights, dim3(128), dim3(256), 0, stream, wqkv, wproj, wsb);

  const int bn_total = in_sizes[0] / SD;   // 2600 (even)
  hipLaunchKernelGGL(ta_fused_kernel, dim3(bn_total / 2), dim3(512), 0, stream,
                     x, wqt, bqkv, wpt, bproj, out);
}

// Round 13
// 290.867 us; speedup vs baseline: 1.2891x; 1.2891x over previous
//
#include <hip/hip_runtime.h>
#include <hip/hip_bf16.h>

// TemporalAttention, MI355X (gfx950), round 13: TWO-KERNEL SPLIT.
// A (ta_qkv_attn): QKV+attention, one head per wave, ONE barrier total.
//   After X-stage each wave is fully independent (private weights, private
//   O-tile transpose in own 4KB LDS, coalesced bf16 att store into the
//   output buffer's per-sequence slot — att[64][256]bf16 = 32KB of the
//   64KB f32 slot, consumed and overwritten by B).
// B (ta_proj): out = att @ Wproj^T + b. Stage att -> phaseC (R11 verbatim)
//   -> staged f32 epilogue. 32KB LDS, 2 barriers, high residency.
// Rationale: 12 rounds show the fused kernel is pinned at ~26us/block by
// barrier-coupled serial chains; splitting removes the coupling (A) and
// makes the GEMM tail a clean streaming kernel (B). att round-trip costs
// ~27us of BW but decouples the phases.

namespace {

constexpr int S_LEN = 64;
constexpr int DM    = 256;
constexpr int SD    = S_LEN * DM;
constexpr int NQKV  = 3 * DM * DM;

typedef float f32x4 __attribute__((ext_vector_type(4)));
typedef short s16x8 __attribute__((ext_vector_type(8)));

union BF2 { __hip_bfloat162 h; unsigned u; };
__device__ __forceinline__ unsigned pkbf2(float a, float b) {
  float2 t; t.x = a; t.y = b;
  BF2 cv; cv.h = __float22bfloat162_rn(t);
  return cv.u;
}

// In-register fragment transpose (verified rounds 3-12).
__device__ __forceinline__ s16x8 xpose_frag(f32x4 a0, f32x4 a1, int c, int g) {
  const int src0 = ((g & 1) << 5) + c;
  const int src1 = src0 + 16;
  unsigned p00 = pkbf2(a0[0], a0[1]);
  unsigned p01 = pkbf2(a0[2], a0[3]);
  unsigned p10 = pkbf2(a1[0], a1[1]);
  unsigned p11 = pkbf2(a1[2], a1[3]);
  const bool hi = (g & 2) != 0;
  unsigned w0a = (unsigned)__shfl((int)p00, src0);
  unsigned w0b = (unsigned)__shfl((int)p10, src0);
  unsigned w1a = (unsigned)__shfl((int)p01, src0);
  unsigned w1b = (unsigned)__shfl((int)p11, src0);
  unsigned w2a = (unsigned)__shfl((int)p00, src1);
  unsigned w2b = (unsigned)__shfl((int)p10, src1);
  unsigned w3a = (unsigned)__shfl((int)p01, src1);
  unsigned w3b = (unsigned)__shfl((int)p11, src1);
  union { s16x8 v; unsigned u[4]; } r;
  r.u[0] = hi ? w0b : w0a;
  r.u[1] = hi ? w1b : w1a;
  r.u[2] = hi ? w2b : w2a;
  r.u[3] = hi ? w3b : w3a;
  return r.v;
}

} // namespace

// ---- prep: f32 weights -> bf16 in workspace (R11 verbatim) ----
__global__ void ta_prep_weights(const float* __restrict__ wqkv,
                                const float* __restrict__ wproj,
                                unsigned short* __restrict__ wsb) {
  const int i = (blockIdx.x * 256 + (int)threadIdx.x) * 4;
  f32x4 v = (i < NQKV) ? *(const f32x4*)(wqkv + i)
                       : *(const f32x4*)(wproj + (i - NQKV));
  unsigned u0 = pkbf2(v[0], v[1]);
  unsigned u1 = pkbf2(v[2], v[3]);
  *(uint2*)(wsb + i) = make_uint2(u0, u1);
}

// ================= Kernel A: QKV + attention =================
__global__ void __launch_bounds__(512, 2)
ta_qkv_attn(const float* __restrict__ x,
            const unsigned short* __restrict__ wq_bf,   // [768][256] bf16
            const float* __restrict__ bqkv,
            float* __restrict__ out)
{
  // LDS 64KB: [0,16384) X (swizzled bf16); [16384 + w*2048) per-wave O tile
  __shared__ __align__(16) unsigned short lds[32768];

  const int bn = blockIdx.x;
  const int tid = (int)threadIdx.x;
  const int w = tid >> 6;       // wave = head
  const int l = tid & 63;
  const int g = l >> 4;
  const int c = l & 15;
  const int c7s = (c & 7) << 3;
  const int h = w;

  const float* __restrict__ xb = x + (size_t)bn * SD;

  // ---- stage X -> LDS bf16 (swizzled; verified R6) ----
#pragma unroll
  for (int it = 0; it < 4; ++it) {
    const int e = (it * 512 + tid) * 8;
    const int row = e >> 8;
    f32x4 a = *(const f32x4*)(xb + e);
    f32x4 b = *(const f32x4*)(xb + e + 4);
    union { s16x8 v; unsigned u[4]; } r;
    r.u[0] = pkbf2(a[0], a[1]); r.u[1] = pkbf2(a[2], a[3]);
    r.u[2] = pkbf2(b[0], b[1]); r.u[3] = pkbf2(b[2], b[3]);
    *(s16x8*)&lds[e ^ ((row & 7) << 3)] = r.v;
  }
  __syncthreads();   // ONLY block-wide barrier in this kernel

  // ---- sweep 1: Q^T, K^T (weights direct from global; L2-hot) ----
  f32x4 aq[2][4], ak[2][4];
#pragma unroll
  for (int t = 0; t < 2; ++t)
#pragma unroll
    for (int nj = 0; nj < 4; ++nj) {
      aq[t][nj] = f32x4{0.f, 0.f, 0.f, 0.f};
      ak[t][nj] = f32x4{0.f, 0.f, 0.f, 0.f};
    }
#pragma unroll
  for (int ks = 0; ks < 8; ++ks) {
    const int kof = ks * 32 + g * 8;
    s16x8 bx[4];
#pragma unroll
    for (int nj = 0; nj < 4; ++nj) {
      const int row = 16 * nj + c;
      bx[nj] = *(const s16x8*)&lds[(row * 256 + kof) ^ c7s];
    }
#pragma unroll
    for (int t = 0; t < 2; ++t) {
      s16x8 awq = *(const s16x8*)&wq_bf[(size_t)((2 * h + t) * 16 + c) * DM + kof];
      s16x8 awk = *(const s16x8*)&wq_bf[(size_t)((256 + 32 * h + 16 * t) + c) * DM + kof];
#pragma unroll
      for (int nj = 0; nj < 4; ++nj) {
        aq[t][nj] = __builtin_amdgcn_mfma_f32_16x16x32_bf16(awq, bx[nj], aq[t][nj], 0, 0, 0);
        ak[t][nj] = __builtin_amdgcn_mfma_f32_16x16x32_bf16(awk, bx[nj], ak[t][nj], 0, 0, 0);
      }
    }
  }
#pragma unroll
  for (int t = 0; t < 2; ++t) {
    f32x4 bq = *(const f32x4*)(bqkv + (2 * h + t) * 16 + 4 * g);
    f32x4 bk = *(const f32x4*)(bqkv + 256 + 32 * h + 16 * t + 4 * g);
#pragma unroll
    for (int nj = 0; nj < 4; ++nj) {
      aq[t][nj] += bq;
      ak[t][nj] += bk;
    }
  }

  // ---- Q,K fragments ----
  s16x8 qa[4], ka[4];
#pragma unroll
  for (int i = 0; i < 4; ++i) {
    qa[i] = xpose_frag(aq[0][i], aq[1][i], c, g);
    ka[i] = xpose_frag(ak[0][i], ak[1][i], c, g);
  }

  // ---- S^T = K @ Q^T ----
  f32x4 sa[4][4];
#pragma unroll
  for (int ki = 0; ki < 4; ++ki)
#pragma unroll
    for (int qi = 0; qi < 4; ++qi) {
      f32x4 z = f32x4{0.f, 0.f, 0.f, 0.f};
      sa[ki][qi] = __builtin_amdgcn_mfma_f32_16x16x32_bf16(ka[ki], qa[qi], z, 0, 0, 0);
    }

  // ---- softmax ----
  const float sc = 0.17677669529663687f * 1.4426950408889634f;
  float inv[4];
#pragma unroll
  for (int qi = 0; qi < 4; ++qi) {
    float m = sa[0][qi][0];
#pragma unroll
    for (int ki = 0; ki < 4; ++ki)
#pragma unroll
      for (int r = 0; r < 4; ++r) m = fmaxf(m, sa[ki][qi][r]);
    m = fmaxf(m, __shfl_xor(m, 16));
    m = fmaxf(m, __shfl_xor(m, 32));
    float s = 0.0f;
#pragma unroll
    for (int ki = 0; ki < 4; ++ki)
#pragma unroll
      for (int r = 0; r < 4; ++r) {
        float pv = exp2f((sa[ki][qi][r] - m) * sc);
        sa[ki][qi][r] = pv;
        s += pv;
      }
    s += __shfl_xor(s, 16);
    s += __shfl_xor(s, 32);
    inv[qi] = 1.0f / s;
  }

  // ---- P fragments ----
  s16x8 pa[4][2];
#pragma unroll
  for (int mi = 0; mi < 4; ++mi) {
    const float iv = inv[mi];
#pragma unroll
    for (int ks2 = 0; ks2 < 2; ++ks2) {
      f32x4 v0 = sa[2 * ks2][mi] * iv;
      f32x4 v1 = sa[2 * ks2 + 1][mi] * iv;
      pa[mi][ks2] = xpose_frag(v0, v1, c, g);
    }
  }

  // ---- sweep 2: V = X @ Wv^T ----
  f32x4 av[4][2];
#pragma unroll
  for (int mt = 0; mt < 4; ++mt)
#pragma unroll
    for (int t = 0; t < 2; ++t) av[mt][t] = f32x4{0.f, 0.f, 0.f, 0.f};
#pragma unroll
  for (int ks = 0; ks < 8; ++ks) {
    const int kof = ks * 32 + g * 8;
    s16x8 bx[4];
#pragma unroll
    for (int mt = 0; mt < 4; ++mt) {
      const int row = 16 * mt + c;
      bx[mt] = *(const s16x8*)&lds[(row * 256 + kof) ^ c7s];
    }
#pragma unroll
    for (int t = 0; t < 2; ++t) {
      s16x8 wv = *(const s16x8*)&wq_bf[(size_t)(512 + 32 * h + 16 * t + c) * DM + kof];
#pragma unroll
      for (int mt = 0; mt < 4; ++mt)
        av[mt][t] = __builtin_amdgcn_mfma_f32_16x16x32_bf16(bx[mt], wv, av[mt][t], 0, 0, 0);
    }
  }
  {
    const float bv0 = bqkv[512 + 32 * h + c];
    const float bv1 = bqkv[512 + 32 * h + 16 + c];
#pragma unroll
    for (int mt = 0; mt < 4; ++mt)
#pragma unroll
      for (int r = 0; r < 4; ++r) {
        av[mt][0][r] += bv0;
        av[mt][1][r] += bv1;
      }
  }

  // ---- V fragments ----
  s16x8 vb[2][2];
#pragma unroll
  for (int nd = 0; nd < 2; ++nd)
#pragma unroll
    for (int ks2 = 0; ks2 < 2; ++ks2)
      vb[nd][ks2] = xpose_frag(av[2 * ks2][nd], av[2 * ks2 + 1][nd], c, g);

  // ---- O = P @ V ----
  f32x4 oa[4][2];
#pragma unroll
  for (int mi = 0; mi < 4; ++mi)
#pragma unroll
    for (int nd = 0; nd < 2; ++nd) oa[mi][nd] = f32x4{0.f, 0.f, 0.f, 0.f};
#pragma unroll
  for (int ks2 = 0; ks2 < 2; ++ks2)
#pragma unroll
    for (int mi = 0; mi < 4; ++mi)
#pragma unroll
      for (int nd = 0; nd < 2; ++nd)
        oa[mi][nd] = __builtin_amdgcn_mfma_f32_16x16x32_bf16(pa[mi][ks2], vb[nd][ks2], oa[mi][nd], 0, 0, 0);

  unsigned obp[4][2][2];
#pragma unroll
  for (int mi = 0; mi < 4; ++mi)
#pragma unroll
    for (int nd = 0; nd < 2; ++nd) {
      obp[mi][nd][0] = pkbf2(oa[mi][nd][0], oa[mi][nd][1]);
      obp[mi][nd][1] = pkbf2(oa[mi][nd][2], oa[mi][nd][3]);
    }

  // ---- per-wave O-tile transpose in private LDS, then coalesced store ----
  unsigned short* lo = lds + 16384 + w * 2048;   // [64 q][32 d]
#pragma unroll
  for (int mi = 0; mi < 4; ++mi)
#pragma unroll
    for (int nd = 0; nd < 2; ++nd)
#pragma unroll
      for (int r = 0; r < 4; ++r) {
        const int q = 16 * mi + 4 * g + r;
        const int d = 16 * nd + c;
        lo[q * 32 + d] = (unsigned short)(obp[mi][nd][r >> 1] >> (16 * (r & 1)));
      }
  asm volatile("s_waitcnt lgkmcnt(0)" ::: "memory");
  __builtin_amdgcn_sched_barrier(0);

  // att slot: first 32KB of this sequence's 64KB f32 output slot
  unsigned short* __restrict__ ab = (unsigned short*)(out + (size_t)bn * SD);
#pragma unroll
  for (int i = 0; i < 4; ++i) {
    const int q = (i * 64 + l) >> 2;
    const int c8 = (l & 3) * 8;
    s16x8 v = *(const s16x8*)&lo[q * 32 + c8];
    *(s16x8*)&ab[q * 256 + w * 32 + c8] = v;
  }
}

// ================= Kernel B: out = att @ Wproj^T + b =================
__global__ void __launch_bounds__(512, 2)
ta_proj(const unsigned short* __restrict__ wp_bf,   // [256][256] bf16
        const float* __restrict__ bproj,
        float* __restrict__ out)
{
  // LDS 32KB: att[64][256] bf16 (swizzled) -> f32 [32][256] epilogue overlay
  __shared__ __align__(16) unsigned short lds[16384];

  const int bn = blockIdx.x;
  const int tid = (int)threadIdx.x;
  const int w = tid >> 6;
  const int l = tid & 63;
  const int g = l >> 4;
  const int c = l & 15;
  const int c7s = (c & 7) << 3;

  const unsigned short* __restrict__ ab = (const unsigned short*)(out + (size_t)bn * SD);

  // ---- stage att -> LDS (bf16 direct, swizzled) ----
#pragma unroll
  for (int it = 0; it < 4; ++it) {
    const int e = (it * 512 + tid) * 8;
    const int row = e >> 8;
    s16x8 v = *(const s16x8*)&ab[e];
    *(s16x8*)&lds[e ^ ((row & 7) << 3)] = v;
  }
  __syncthreads();

  // ---- phaseC: out^T = Wproj @ att^T (R11 verbatim, W direct global) ----
  f32x4 pacc[2][4];
#pragma unroll
  for (int ti = 0; ti < 2; ++ti)
#pragma unroll
    for (int nj = 0; nj < 4; ++nj) pacc[ti][nj] = f32x4{0.f, 0.f, 0.f, 0.f};

#pragma unroll
  for (int ks = 0; ks < 8; ++ks) {
    const int kof = ks * 32 + 8 * g;
    s16x8 bx[4];
#pragma unroll
    for (int nj = 0; nj < 4; ++nj) {
      const int row = 16 * nj + c;
      bx[nj] = *(const s16x8*)&lds[(row * 256 + kof) ^ c7s];
    }
#pragma unroll
    for (int ti = 0; ti < 2; ++ti) {
      const int e = (2 * w + ti) * 16 + c;
      s16x8 aw = *(const s16x8*)&wp_bf[(size_t)e * DM + kof];
#pragma unroll
      for (int nj = 0; nj < 4; ++nj)
        pacc[ti][nj] = __builtin_amdgcn_mfma_f32_16x16x32_bf16(aw, bx[nj], pacc[ti][nj], 0, 0, 0);
    }
  }
  __syncthreads();   // att reads done; reuse LDS as f32 half-tiles

  // ---- epilogue: two 32-row f32 halves, staged + coalesced stores ----
  float* ldsf = (float*)lds;
  float* __restrict__ ob = out + (size_t)bn * SD;
#pragma unroll
  for (int H = 0; H < 2; ++H) {
#pragma unroll
    for (int ti = 0; ti < 2; ++ti) {
      const int e0 = (2 * w + ti) * 16 + 4 * g;
      f32x4 bp = *(const f32x4*)(bproj + e0);
#pragma unroll
      for (int nj = 2 * H; nj < 2 * H + 2; ++nj) {
        const int lr = 16 * (nj - 2 * H) + c;
        f32x4 v;
        v[0] = pacc[ti][nj][0] + bp[0];
        v[1] = pacc[ti][nj][1] + bp[1];
        v[2] = pacc[ti][nj][2] + bp[2];
        v[3] = pacc[ti][nj][3] + bp[3];
        *(f32x4*)&ldsf[(lr * 256 + e0) ^ ((lr & 7) << 2)] = v;
      }
    }
    __syncthreads();
#pragma unroll
    for (int it = 0; it < 4; ++it) {
      const int i = (it * 512 + tid) * 4;
      const int lr = i >> 8;
      f32x4 v = *(const f32x4*)&ldsf[i ^ ((lr & 7) << 2)];
      *(f32x4*)(ob + H * 8192 + i) = v;
    }
    if (H == 0) __syncthreads();
  }
}

extern "C" void kernel_launch(void* const* d_in, const int* in_sizes, int n_in,
                              void* d_out, int out_size, void* d_ws, size_t ws_size,
                              hipStream_t stream) {
  (void)n_in; (void)ws_size; (void)out_size;
  const float* x     = (const float*)d_in[0];
  const float* wqkv  = (const float*)d_in[1];
  const float* bqkv  = (const float*)d_in[2];
  const float* wproj = (const float*)d_in[3];
  const float* bproj = (const float*)d_in[4];
  float* out = (float*)d_out;

  unsigned short* wsb = (unsigned short*)d_ws;
  const unsigned short* wq_bf = wsb;
  const unsigned short* wp_bf = wsb + NQKV;

  hipLaunchKernelGGL(ta_prep_weights, dim3(256), dim3(256), 0, stream, wqkv, wproj, wsb);

  const int bn_total = in_sizes[0] / SD;  // 2600
  hipLaunchKernelGGL(ta_qkv_attn, dim3(bn_total), dim3(512), 0, stream,
                     x, wq_bf, bqkv, out);
  hipLaunchKernelGGL(ta_proj, dim3(bn_total), dim3(512), 0, stream,
                     wp_bf, bproj, out);
}

// Round 14
// 237.489 us; speedup vs baseline: 1.5788x; 1.2248x over previous
//
#include <hip/hip_runtime.h>
#include <hip/hip_bf16.h>

// TemporalAttention fused kernel for MI355X (gfx950), round 14.
// = Round 11 (best: 242us) + NON-TEMPORAL hints on the two streaming flows
// (X stage loads, output stores). Theory: the 170MB X + 166MB out streams
// thrash the 4MB/XCD L2, evicting the 512KB weight set to L3 (~600cy). The
// per-wave chain of 16 ks-units x 6 dependent weight loads x 600cy = 57.6k
// cy = 24us/block — exactly the invariant wall seen in R2-R13. nt loads/
// stores (evict-first) keep weights L2-resident (~200cy) -> chain ~3x shorter.

namespace {

constexpr int S_LEN = 64;
constexpr int DM    = 256;
constexpr int SD    = S_LEN * DM;
constexpr int NQKV  = 3 * DM * DM;

typedef float f32x4 __attribute__((ext_vector_type(4)));
typedef short s16x8 __attribute__((ext_vector_type(8)));

union BF2 { __hip_bfloat162 h; unsigned u; };
__device__ __forceinline__ unsigned pkbf2(float a, float b) {
  float2 t; t.x = a; t.y = b;
  BF2 cv; cv.h = __float22bfloat162_rn(t);
  return cv.u;
}

// lgkm-only block barrier (R11-verified): does NOT drain vmcnt.
__device__ __forceinline__ void bar_lgkm() {
  asm volatile("s_waitcnt lgkmcnt(0)" ::: "memory");
  __builtin_amdgcn_sched_barrier(0);
  __builtin_amdgcn_s_barrier();
  __builtin_amdgcn_sched_barrier(0);
}

// In-register fragment transpose (verified rounds 3-13).
__device__ __forceinline__ s16x8 xpose_frag(f32x4 a0, f32x4 a1, int c, int g) {
  const int src0 = ((g & 1) << 5) + c;
  const int src1 = src0 + 16;
  unsigned p00 = pkbf2(a0[0], a0[1]);
  unsigned p01 = pkbf2(a0[2], a0[3]);
  unsigned p10 = pkbf2(a1[0], a1[1]);
  unsigned p11 = pkbf2(a1[2], a1[3]);
  const bool hi = (g & 2) != 0;
  unsigned w0a = (unsigned)__shfl((int)p00, src0);
  unsigned w0b = (unsigned)__shfl((int)p10, src0);
  unsigned w1a = (unsigned)__shfl((int)p01, src0);
  unsigned w1b = (unsigned)__shfl((int)p11, src0);
  unsigned w2a = (unsigned)__shfl((int)p00, src1);
  unsigned w2b = (unsigned)__shfl((int)p10, src1);
  unsigned w3a = (unsigned)__shfl((int)p01, src1);
  unsigned w3b = (unsigned)__shfl((int)p11, src1);
  union { s16x8 v; unsigned u[4]; } r;
  r.u[0] = hi ? w0b : w0a;
  r.u[1] = hi ? w1b : w1a;
  r.u[2] = hi ? w2b : w2a;
  r.u[3] = hi ? w3b : w3a;
  return r.v;
}

// Weight LDS addressing (verified R9/R11): per-ks image [rows][32 cols] bf16,
// 16B-unit swizzle u' = g ^ ((row>>1)&3) => 2-way aliasing (free, m136).
__device__ __forceinline__ int wswz(int row, int u) {
  return row * 32 + ((u ^ ((row >> 1) & 3)) << 3);
}

} // namespace

// ---- prep: f32 weights -> bf16 in workspace ----
__global__ void ta_prep_weights(const float* __restrict__ wqkv,
                                const float* __restrict__ wproj,
                                unsigned short* __restrict__ wsb) {
  const int i = (blockIdx.x * 256 + (int)threadIdx.x) * 4;
  f32x4 v = (i < NQKV) ? *(const f32x4*)(wqkv + i)
                       : *(const f32x4*)(wproj + (i - NQKV));
  unsigned u0 = pkbf2(v[0], v[1]);
  unsigned u1 = pkbf2(v[2], v[3]);
  *(uint2*)(wsb + i) = make_uint2(u0, u1);
}

__global__ void __launch_bounds__(512, 1)
ta_fused_kernel(const float* __restrict__ x,
                const unsigned short* __restrict__ wq_bf,   // [768][256] bf16
                const float* __restrict__ bqkv,
                const unsigned short* __restrict__ wp_bf,   // [256][256] bf16
                const float* __restrict__ bproj,
                float* __restrict__ out)
{
  // LDS 128KB (65536 shorts):
  //  [0,16384)      xls[64][256] bf16 X (swizzled) -> att overlay
  //  [16384,40960)  W stage buffer 0 (48KB: [768][32] per-ks image)
  //  [40960,65536)  W stage buffer 1
  //  epilogue: f32 [32][256] overlay on buffer-0 region
  __shared__ __align__(16) unsigned short lds[65536];

  const int bn = blockIdx.x;
  const int tid = (int)threadIdx.x;
  const int w = tid >> 6;       // wave 0..7 = head
  const int l = tid & 63;
  const int g = l >> 4;
  const int c = l & 15;
  const int c7s = (c & 7) << 3;
  const int h = w;

  unsigned short* __restrict__ xls = lds;
  unsigned short* wbuf[2] = { lds + 16384, lds + 40960 };

  const float* __restrict__ xb = x + (size_t)bn * SD;

  // ---- issue W[ks=0] staging loads (fly under X stage) ----
  s16x8 wst[6];
#pragma unroll
  for (int i = 0; i < 6; ++i) {
    const int idx = i * 512 + tid, row = idx >> 2, gl = idx & 3;
    wst[i] = *(const s16x8*)&wq_bf[row * 256 + 0 * 32 + gl * 8];
  }

  // ---- stage X -> LDS bf16 (swizzled; NT loads: don't thrash L2) ----
#pragma unroll
  for (int it = 0; it < 4; ++it) {
    const int e = (it * 512 + tid) * 8;
    const int row = e >> 8;
    f32x4 a = __builtin_nontemporal_load((const f32x4*)(xb + e));
    f32x4 b = __builtin_nontemporal_load((const f32x4*)(xb + e + 4));
    union { s16x8 v; unsigned u[4]; } r;
    r.u[0] = pkbf2(a[0], a[1]); r.u[1] = pkbf2(a[2], a[3]);
    r.u[2] = pkbf2(b[0], b[1]); r.u[3] = pkbf2(b[2], b[3]);
    *(s16x8*)&xls[e ^ ((row & 7) << 3)] = r.v;
  }
  bar_lgkm();                      // X visible; wst0 loads still in flight

  // ---- W prologue: write buf0 = W[0]; issue W[1] ----
#pragma unroll
  for (int i = 0; i < 6; ++i) {
    const int idx = i * 512 + tid, row = idx >> 2, gl = idx & 3;
    *(s16x8*)&wbuf[0][wswz(row, gl)] = wst[i];
  }
#pragma unroll
  for (int i = 0; i < 6; ++i) {
    const int idx = i * 512 + tid, row = idx >> 2, gl = idx & 3;
    wst[i] = *(const s16x8*)&wq_bf[row * 256 + 1 * 32 + gl * 8];
  }
  bar_lgkm();                      // buf0 ready; W1 loads in flight

  // ---- merged Q/K/V sweep: 8 ks-steps, lgkm-only barriers ----
  f32x4 aq[2][4], ak[2][4], av[4][2];
#pragma unroll
  for (int t = 0; t < 2; ++t)
#pragma unroll
    for (int nj = 0; nj < 4; ++nj) {
      aq[t][nj] = f32x4{0.f, 0.f, 0.f, 0.f};
      ak[t][nj] = f32x4{0.f, 0.f, 0.f, 0.f};
    }
#pragma unroll
  for (int mt = 0; mt < 4; ++mt)
#pragma unroll
    for (int t = 0; t < 2; ++t) av[mt][t] = f32x4{0.f, 0.f, 0.f, 0.f};

#pragma unroll
  for (int ks = 0; ks < 8; ++ks) {
    const unsigned short* wb = wbuf[ks & 1];
    const int kof = ks * 32 + g * 8;
    s16x8 bx[4];
#pragma unroll
    for (int nj = 0; nj < 4; ++nj) {
      const int row = 16 * nj + c;
      bx[nj] = *(const s16x8*)&xls[(row * 256 + kof) ^ c7s];
    }
#pragma unroll
    for (int t = 0; t < 2; ++t) {
      s16x8 awq = *(const s16x8*)&wb[wswz((2 * h + t) * 16 + c, g)];
      s16x8 awk = *(const s16x8*)&wb[wswz(256 + 32 * h + 16 * t + c, g)];
      s16x8 awv = *(const s16x8*)&wb[wswz(512 + 32 * h + 16 * t + c, g)];
#pragma unroll
      for (int nj = 0; nj < 4; ++nj) {
        aq[t][nj] = __builtin_amdgcn_mfma_f32_16x16x32_bf16(awq, bx[nj], aq[t][nj], 0, 0, 0);
        ak[t][nj] = __builtin_amdgcn_mfma_f32_16x16x32_bf16(awk, bx[nj], ak[t][nj], 0, 0, 0);
        av[nj][t] = __builtin_amdgcn_mfma_f32_16x16x32_bf16(bx[nj], awv, av[nj][t], 0, 0, 0);
      }
    }
    if (ks < 7) {   // write next buffer (counted vmcnt wait, not 0)
#pragma unroll
      for (int i = 0; i < 6; ++i) {
        const int idx = i * 512 + tid, row = idx >> 2, gl = idx & 3;
        *(s16x8*)&wbuf[(ks + 1) & 1][wswz(row, gl)] = wst[i];
      }
    }
    if (ks < 6) {   // issue loads for ks+2 (stay in flight across barrier)
#pragma unroll
      for (int i = 0; i < 6; ++i) {
        const int idx = i * 512 + tid, row = idx >> 2, gl = idx & 3;
        wst[i] = *(const s16x8*)&wq_bf[row * 256 + (ks + 2) * 32 + gl * 8];
      }
    }
    bar_lgkm();
  }

  // ---- issue phaseC W[0] loads early (fly under the attention middle) ----
  s16x8 pst[2];
#pragma unroll
  for (int i = 0; i < 2; ++i) {
    const int idx = i * 512 + tid, row = idx >> 2, gl = idx & 3;
    pst[i] = *(const s16x8*)&wp_bf[row * 256 + 0 * 32 + gl * 8];
  }

  // ---- biases ----
#pragma unroll
  for (int t = 0; t < 2; ++t) {
    f32x4 bq = *(const f32x4*)(bqkv + (2 * h + t) * 16 + 4 * g);
    f32x4 bk = *(const f32x4*)(bqkv + 256 + 32 * h + 16 * t + 4 * g);
#pragma unroll
    for (int nj = 0; nj < 4; ++nj) {
      aq[t][nj] += bq;
      ak[t][nj] += bk;
    }
  }
  {
    const float bv0 = bqkv[512 + 32 * h + c];
    const float bv1 = bqkv[512 + 32 * h + 16 + c];
#pragma unroll
    for (int mt = 0; mt < 4; ++mt)
#pragma unroll
      for (int r = 0; r < 4; ++r) {
        av[mt][0][r] += bv0;
        av[mt][1][r] += bv1;
      }
  }

  // ---- Q,K fragments (in-register transpose) ----
  s16x8 qa[4], ka[4];
#pragma unroll
  for (int i = 0; i < 4; ++i) {
    qa[i] = xpose_frag(aq[0][i], aq[1][i], c, g);
    ka[i] = xpose_frag(ak[0][i], ak[1][i], c, g);
  }

  // ---- S^T = K @ Q^T ----
  f32x4 sa[4][4];
#pragma unroll
  for (int ki = 0; ki < 4; ++ki)
#pragma unroll
    for (int qi = 0; qi < 4; ++qi) {
      f32x4 z = f32x4{0.f, 0.f, 0.f, 0.f};
      sa[ki][qi] = __builtin_amdgcn_mfma_f32_16x16x32_bf16(ka[ki], qa[qi], z, 0, 0, 0);
    }

  // ---- softmax over keys ----
  const float sc = 0.17677669529663687f * 1.4426950408889634f;
  float inv[4];
#pragma unroll
  for (int qi = 0; qi < 4; ++qi) {
    float m = sa[0][qi][0];
#pragma unroll
    for (int ki = 0; ki < 4; ++ki)
#pragma unroll
      for (int r = 0; r < 4; ++r) m = fmaxf(m, sa[ki][qi][r]);
    m = fmaxf(m, __shfl_xor(m, 16));
    m = fmaxf(m, __shfl_xor(m, 32));
    float s = 0.0f;
#pragma unroll
    for (int ki = 0; ki < 4; ++ki)
#pragma unroll
      for (int r = 0; r < 4; ++r) {
        float pv = exp2f((sa[ki][qi][r] - m) * sc);
        sa[ki][qi][r] = pv;
        s += pv;
      }
    s += __shfl_xor(s, 16);
    s += __shfl_xor(s, 32);
    inv[qi] = 1.0f / s;
  }

  // ---- P fragments ----
  s16x8 pa[4][2];
#pragma unroll
  for (int mi = 0; mi < 4; ++mi) {
    const float iv = inv[mi];
#pragma unroll
    for (int ks2 = 0; ks2 < 2; ++ks2) {
      f32x4 v0 = sa[2 * ks2][mi] * iv;
      f32x4 v1 = sa[2 * ks2 + 1][mi] * iv;
      pa[mi][ks2] = xpose_frag(v0, v1, c, g);
    }
  }

  // ---- V fragments ----
  s16x8 vb[2][2];
#pragma unroll
  for (int nd = 0; nd < 2; ++nd)
#pragma unroll
    for (int ks2 = 0; ks2 < 2; ++ks2)
      vb[nd][ks2] = xpose_frag(av[2 * ks2][nd], av[2 * ks2 + 1][nd], c, g);

  // ---- O = P @ V ----
  f32x4 oa[4][2];
#pragma unroll
  for (int mi = 0; mi < 4; ++mi)
#pragma unroll
    for (int nd = 0; nd < 2; ++nd) oa[mi][nd] = f32x4{0.f, 0.f, 0.f, 0.f};
#pragma unroll
  for (int ks2 = 0; ks2 < 2; ++ks2)
#pragma unroll
    for (int mi = 0; mi < 4; ++mi)
#pragma unroll
      for (int nd = 0; nd < 2; ++nd)
        oa[mi][nd] = __builtin_amdgcn_mfma_f32_16x16x32_bf16(pa[mi][ks2], vb[nd][ks2], oa[mi][nd], 0, 0, 0);

  unsigned obp[4][2][2];
#pragma unroll
  for (int mi = 0; mi < 4; ++mi)
#pragma unroll
    for (int nd = 0; nd < 2; ++nd) {
      obp[mi][nd][0] = pkbf2(oa[mi][nd][0], oa[mi][nd][1]);
      obp[mi][nd][1] = pkbf2(oa[mi][nd][2], oa[mi][nd][3]);
    }

  // ---- scatter att over X region; stage phaseC buf0; one barrier ----
#pragma unroll
  for (int mi = 0; mi < 4; ++mi)
#pragma unroll
    for (int nd = 0; nd < 2; ++nd)
#pragma unroll
      for (int r = 0; r < 4; ++r) {
        const int q = 16 * mi + 4 * g + r;
        const int feat = h * 32 + 16 * nd + c;
        unsigned val = obp[mi][nd][r >> 1] >> (16 * (r & 1));
        xls[(q * 256 + feat) ^ ((q & 7) << 3)] = (unsigned short)val;
      }
#pragma unroll
  for (int i = 0; i < 2; ++i) {
    const int idx = i * 512 + tid, row = idx >> 2, gl = idx & 3;
    *(s16x8*)&wbuf[0][wswz(row, gl)] = pst[i];
  }
#pragma unroll
  for (int i = 0; i < 2; ++i) {
    const int idx = i * 512 + tid, row = idx >> 2, gl = idx & 3;
    pst[i] = *(const s16x8*)&wp_bf[row * 256 + 1 * 32 + gl * 8];
  }
  bar_lgkm();                      // att + phaseC buf0 visible; P1 in flight

  // ---- Phase C: out^T = Wproj @ att^T, weights from staged LDS ----
  f32x4 pacc[2][4];
#pragma unroll
  for (int ti = 0; ti < 2; ++ti)
#pragma unroll
    for (int nj = 0; nj < 4; ++nj) pacc[ti][nj] = f32x4{0.f, 0.f, 0.f, 0.f};

#pragma unroll
  for (int ks = 0; ks < 8; ++ks) {
    const unsigned short* wb = wbuf[ks & 1];
    const int kof = ks * 32 + 8 * g;
    s16x8 bx[4];
#pragma unroll
    for (int nj = 0; nj < 4; ++nj) {
      const int row = 16 * nj + c;
      bx[nj] = *(const s16x8*)&xls[(row * 256 + kof) ^ c7s];
    }
#pragma unroll
    for (int ti = 0; ti < 2; ++ti) {
      s16x8 aw = *(const s16x8*)&wb[wswz((2 * w + ti) * 16 + c, g)];
#pragma unroll
      for (int nj = 0; nj < 4; ++nj)
        pacc[ti][nj] = __builtin_amdgcn_mfma_f32_16x16x32_bf16(aw, bx[nj], pacc[ti][nj], 0, 0, 0);
    }
    if (ks < 7) {
#pragma unroll
      for (int i = 0; i < 2; ++i) {
        const int idx = i * 512 + tid, row = idx >> 2, gl = idx & 3;
        *(s16x8*)&wbuf[(ks + 1) & 1][wswz(row, gl)] = pst[i];
      }
    }
    if (ks < 6) {
#pragma unroll
      for (int i = 0; i < 2; ++i) {
        const int idx = i * 512 + tid, row = idx >> 2, gl = idx & 3;
        pst[i] = *(const s16x8*)&wp_bf[row * 256 + (ks + 2) * 32 + gl * 8];
      }
    }
    bar_lgkm();
  }

  // ---- epilogue: two 32-row f32 halves (overlay W buf0), NT stores ----
  float* ldsf = (float*)wbuf[0];
  float* __restrict__ ob = out + (size_t)bn * SD;
#pragma unroll
  for (int H = 0; H < 2; ++H) {
#pragma unroll
    for (int ti = 0; ti < 2; ++ti) {
      const int e0 = (2 * w + ti) * 16 + 4 * g;
      f32x4 bp = *(const f32x4*)(bproj + e0);
#pragma unroll
      for (int nj = 2 * H; nj < 2 * H + 2; ++nj) {
        const int lr = 16 * (nj - 2 * H) + c;
        f32x4 v;
        v[0] = pacc[ti][nj][0] + bp[0];
        v[1] = pacc[ti][nj][1] + bp[1];
        v[2] = pacc[ti][nj][2] + bp[2];
        v[3] = pacc[ti][nj][3] + bp[3];
        *(f32x4*)&ldsf[(lr * 256 + e0) ^ ((lr & 7) << 2)] = v;
      }
    }
    bar_lgkm();
#pragma unroll
    for (int it = 0; it < 4; ++it) {
      const int i = (it * 512 + tid) * 4;
      const int lr = i >> 8;
      f32x4 v = *(const f32x4*)&ldsf[i ^ ((lr & 7) << 2)];
      __builtin_nontemporal_store(v, (f32x4*)(ob + H * 8192 + i));
    }
    if (H == 0) bar_lgkm();
  }
}

extern "C" void kernel_launch(void* const* d_in, const int* in_sizes, int n_in,
                              void* d_out, int out_size, void* d_ws, size_t ws_size,
                              hipStream_t stream) {
  (void)n_in; (void)ws_size; (void)out_size;
  const float* x     = (const float*)d_in[0];
  const float* wqkv  = (const float*)d_in[1];
  const float* bqkv  = (const float*)d_in[2];
  const float* wproj = (const float*)d_in[3];
  const float* bproj = (const float*)d_in[4];
  float* out = (float*)d_out;

  unsigned short* wsb = (unsigned short*)d_ws;
  const unsigned short* wq_bf = wsb;
  const unsigned short* wp_bf = wsb + NQKV;

  hipLaunchKernelGGL(ta_prep_weights, dim3(256), dim3(256), 0, stream, wqkv, wproj, wsb);

  const int bn_total = in_sizes[0] / SD;  // 2600
  hipLaunchKernelGGL(ta_fused_kernel, dim3(bn_total), dim3(512), 0, stream,
                     x, wq_bf, bqkv, wp_bf, bproj, out);
}